// Round 2
// baseline (190.847 us; speedup 1.0000x reference)
//
#include <hip/hip_runtime.h>

// Segment mean-pooling: feats [B,S,H] f32, segment_ids [B,S] i32 sorted
// non-decreasing in [0,G). Outputs flat-concat: grouped [B,G,H] f32, then
// counts [B,G] written as float values.
#define BB 8
#define SS 8192
#define HH 512
#define GG 1024
#define GPB 2   // groups per block: 4096 blocks -> ~16 resident/CU with
                // backfill => dynamic per-CU load balancing (2048 blocks
                // = exactly 8/CU static, duration = max per-CU Poisson draw)

typedef float f32x4 __attribute__((ext_vector_type(4)));

// Single fused kernel: one block per (b, GPB consecutive groups).
// Group boundaries found in-block by per-lane binary search over the sorted
// ids row (13 L2-hot broadcast loads). Main loop: 128 lanes * float4 =
// 2048B = full H row, perfectly coalesced per token, 4-deep unrolled.
// Tail (<=3 tokens, wave-uniform count) unrolled under scalar branches so
// its loads issue back-to-back (the old scalar loop had a loop-carried
// dependency -> 1 load in flight for ~19% of tokens).
// __launch_bounds__(128,8): cap VGPRs at 64 so 16 blocks/CU co-reside.
__global__ __launch_bounds__(128, 8) void group_mean_fused(
    const f32x4* __restrict__ feats,
    const int*   __restrict__ ids,
    f32x4*       __restrict__ grouped,
    float*       __restrict__ counts)
{
    const int g0 = blockIdx.x * GPB;
    const int b  = blockIdx.y;
    const int t  = threadIdx.x;   // 0..127
    const int lane = t & 63;

    const int* __restrict__ row = ids + (size_t)b * SS;

    // lower_bound(row, g) for g = g0 + lane (clamped at g0+GPB so all lanes
    // run the same loop; lanes 0..GPB hold the GPB+1 boundaries).
    const int g = g0 + (lane < GPB ? lane : GPB);
    int lo = 0, hi = SS;
    while (lo < hi) {
        const int mid = (lo + hi) >> 1;   // always in-bounds
        if (row[mid] < g) lo = mid + 1; else hi = mid;
    }
    // lo == first index with row[lo] >= g (== SS if g beyond all ids).

    int o[GPB + 1];
    #pragma unroll
    for (int i = 0; i <= GPB; ++i) o[i] = __shfl(lo, i);

    const f32x4* __restrict__ fb = feats + (size_t)b * SS * (HH / 4);

    #pragma unroll
    for (int i = 0; i < GPB; ++i) {
        const int lo_i = o[i], hi_i = o[i + 1];
        const int n = hi_i - lo_i;
        f32x4 a0 = 0.f, a1 = 0.f, a2 = 0.f, a3 = 0.f;
        int s = lo_i;
        for (; s + 3 < hi_i; s += 4) {
            f32x4 v0 = __builtin_nontemporal_load(&fb[(size_t)(s    ) * (HH / 4) + t]);
            f32x4 v1 = __builtin_nontemporal_load(&fb[(size_t)(s + 1) * (HH / 4) + t]);
            f32x4 v2 = __builtin_nontemporal_load(&fb[(size_t)(s + 2) * (HH / 4) + t]);
            f32x4 v3 = __builtin_nontemporal_load(&fb[(size_t)(s + 3) * (HH / 4) + t]);
            a0 += v0; a1 += v1; a2 += v2; a3 += v3;
        }
        // Tail: rem in [0,3], wave-uniform (o[] identical across lanes) ->
        // scalar branches, no divergence; loads overlap (issue-then-waitcnt).
        if (s < hi_i) {
            f32x4 v0 = __builtin_nontemporal_load(&fb[(size_t)s * (HH / 4) + t]);
            if (s + 1 < hi_i) {
                f32x4 v1 = __builtin_nontemporal_load(&fb[(size_t)(s + 1) * (HH / 4) + t]);
                if (s + 2 < hi_i) {
                    a2 += __builtin_nontemporal_load(&fb[(size_t)(s + 2) * (HH / 4) + t]);
                }
                a1 += v1;
            }
            a0 += v0;
        }
        const float inv = (n > 0) ? (1.0f / (float)n) : 0.0f;
        f32x4 r = ((a0 + a1) + (a2 + a3)) * inv;
        __builtin_nontemporal_store(r, &grouped[((size_t)b * GG + g0 + i) * (HH / 4) + t]);
        if (t == 0) counts[(size_t)b * GG + g0 + i] = (float)n;
    }
}

extern "C" void kernel_launch(void* const* d_in, const int* in_sizes, int n_in,
                              void* d_out, int out_size, void* d_ws, size_t ws_size,
                              hipStream_t stream) {
    const float* feats = (const float*)d_in[0];
    const int*   ids   = (const int*)d_in[1];
    float* grouped = (float*)d_out;
    float* counts  = grouped + (size_t)BB * GG * HH;

    dim3 grid(GG / GPB, BB);
    group_mean_fused<<<grid, 128, 0, stream>>>((const f32x4*)feats, ids,
                                               (f32x4*)grouped, counts);
}